// Round 1
// baseline (269.461 us; speedup 1.0000x reference)
//
#include <hip/hip_runtime.h>
#include <hip/hip_bf16.h>
#include <math.h>

// Problem constants
#define BATCH 2
#define SEQ 2048
#define DI 2048            // d_inner
#define DS 16              // d_state
#define DR 64              // dt_rank
#define P 96               // DR + 2*DS
#define BT_ROWS 4096       // BATCH*SEQ
#define NCH 32             // time chunks
#define CL 64              // chunk length (NCH*CL == SEQ)
#define KS 8               // split-K segments for proj1
#define KSEG 256           // 2048 / KS

// Workspace layout (floats)
#define WS_XZ     0                      // 4096*96        = 393216
#define WS_PARTS  393216                 // KS*4096*96     = 3145728
#define WS_DTWT   3538944                // 64*2048        = 131072
#define WS_HEND   3670016                // 2*32*16*2048   = 2097152
#define WS_CUMA   5767168                // 2*32*16*2048   = 2097152
// total: 7864320 floats = 31.5 MB

// ---------------- K0: transpose dt_proj_w (2048x64) -> dtwT (64x2048) ----
__global__ __launch_bounds__(256) void k_transpose(const float* __restrict__ dtw,
                                                   float* __restrict__ dtwT) {
    int i = blockIdx.x * 256 + threadIdx.x;   // 131072 threads
    int d = i & (DI - 1);
    int r = i >> 11;
    dtwT[r * DI + d] = dtw[d * DR + r];       // coalesced write, strided read (0.5 MB, cheap)
}

// ---------------- K1: xz partials, split-K GEMM  C[bt][p] = sum_k x[bt][k]*w[p][k]
__global__ __launch_bounds__(256) void k_proj1(const float* __restrict__ x,
                                               const float* __restrict__ w,
                                               float* __restrict__ parts) {
    __shared__ float Xt[32][64 + 4];   // [k][row], pad 4 -> 272B stride (16B aligned)
    __shared__ float Wt[32][96 + 4];   // [k][p]
    const int tid = threadIdx.x;
    const int tx = tid & 31;           // col group: p = tx*3 + {0,1,2}
    const int ty = tid >> 5;           // row group: r = ty*8 + j
    const int row0 = blockIdx.x * 64;
    const int k0 = blockIdx.y * KSEG;

    float acc[8][3];
#pragma unroll
    for (int j = 0; j < 8; ++j) { acc[j][0] = 0.f; acc[j][1] = 0.f; acc[j][2] = 0.f; }

    const int kk = tid & 31;
    const int rr = tid >> 5;

    for (int kt = 0; kt < KSEG; kt += 32) {
        // stage X tile (64 rows x 32 k), coalesced global reads
#pragma unroll
        for (int j = 0; j < 8; ++j) {
            int r = rr + 8 * j;
            Xt[kk][r] = x[(size_t)(row0 + r) * DI + k0 + kt + kk];
        }
        // stage W tile (32 k x 96 p), coalesced per row
#pragma unroll
        for (int j = 0; j < 12; ++j) {
            int p = rr + 8 * j;
            Wt[kk][p] = w[(size_t)p * DI + k0 + kt + kk];
        }
        __syncthreads();
#pragma unroll
        for (int k = 0; k < 32; ++k) {
            float4 xa = *(const float4*)&Xt[k][ty * 8];
            float4 xb = *(const float4*)&Xt[k][ty * 8 + 4];
            float wv0 = Wt[k][tx * 3 + 0];
            float wv1 = Wt[k][tx * 3 + 1];
            float wv2 = Wt[k][tx * 3 + 2];
            float xv[8] = {xa.x, xa.y, xa.z, xa.w, xb.x, xb.y, xb.z, xb.w};
#pragma unroll
            for (int j = 0; j < 8; ++j) {
                acc[j][0] = fmaf(xv[j], wv0, acc[j][0]);
                acc[j][1] = fmaf(xv[j], wv1, acc[j][1]);
                acc[j][2] = fmaf(xv[j], wv2, acc[j][2]);
            }
        }
        __syncthreads();
    }
    float* out = parts + (size_t)blockIdx.y * BT_ROWS * P;
#pragma unroll
    for (int j = 0; j < 8; ++j) {
        int r = row0 + ty * 8 + j;
        out[(size_t)r * P + tx * 3 + 0] = acc[j][0];
        out[(size_t)r * P + tx * 3 + 1] = acc[j][1];
        out[(size_t)r * P + tx * 3 + 2] = acc[j][2];
    }
}

// ---------------- K1r: reduce split-K partials -> xz ----------------------
__global__ __launch_bounds__(256) void k_reduce(const float* __restrict__ parts,
                                                float* __restrict__ xz) {
    int i = blockIdx.x * 256 + threadIdx.x;   // 393216 threads
    float s = 0.f;
#pragma unroll
    for (int k = 0; k < KS; ++k) s += parts[(size_t)k * BT_ROWS * P + i];
    xz[i] = s;
}

// ---------------- K2: delta = softplus(draw @ dtw^T + bias) ---------------
__global__ __launch_bounds__(256) void k_proj2(const float* __restrict__ xz,
                                               const float* __restrict__ dtwT,
                                               const float* __restrict__ bias,
                                               float* __restrict__ delta) {
    __shared__ float draw_s[64][16];   // [r][row]
    const int tid = threadIdx.x;
    const int bt0 = blockIdx.x * 16;
    const int d = blockIdx.y * 256 + tid;

    for (int i = tid; i < 1024; i += 256) {
        int r = i & 63;
        int row = i >> 6;
        draw_s[r][row] = xz[(size_t)(bt0 + row) * P + r];
    }
    __syncthreads();

    float acc[16];
#pragma unroll
    for (int j = 0; j < 16; ++j) acc[j] = 0.f;

    for (int r = 0; r < 64; ++r) {
        float w = dtwT[(size_t)r * DI + d];
        const float4* dr = (const float4*)&draw_s[r][0];
        float4 a0 = dr[0], a1 = dr[1], a2 = dr[2], a3 = dr[3];
        float vals[16] = {a0.x, a0.y, a0.z, a0.w, a1.x, a1.y, a1.z, a1.w,
                          a2.x, a2.y, a2.z, a2.w, a3.x, a3.y, a3.z, a3.w};
#pragma unroll
        for (int j = 0; j < 16; ++j) acc[j] = fmaf(vals[j], w, acc[j]);
    }
    float b = bias[d];
#pragma unroll
    for (int j = 0; j < 16; ++j) {
        float v = acc[j] + b;
        float sp = (v > 20.f) ? v : log1pf(__expf(v));
        delta[(size_t)(bt0 + j) * DI + d] = sp;
    }
}

// ---------------- K3: per-chunk local scan (h0=0) -> h_end, cumA ----------
__global__ __launch_bounds__(256) void k_scan1(const float* __restrict__ delta,
                                               const float* __restrict__ x,
                                               const float* __restrict__ xz,
                                               const float* __restrict__ A_log,
                                               float* __restrict__ hend,
                                               float* __restrict__ cumA) {
    __shared__ float Bs[CL][DS];
    const int tid = threadIdx.x;
    const int d = blockIdx.x * 256 + tid;
    const int c = blockIdx.y;
    const int b = blockIdx.z;
    const int btbase = b * SEQ + c * CL;

    for (int i = tid; i < CL * DS; i += 256) {
        int t = i >> 4;
        int n = i & 15;
        Bs[t][n] = xz[(size_t)(btbase + t) * P + DR + n];
    }
    float a2[16];
#pragma unroll
    for (int n = 0; n < 16; ++n)
        a2[n] = -__expf(A_log[(size_t)d * DS + n]) * 1.4426950408889634f;  // *log2(e)

    float h[16];
#pragma unroll
    for (int n = 0; n < 16; ++n) h[n] = 0.f;
    float sd = 0.f;
    __syncthreads();

    for (int t = 0; t < CL; ++t) {
        size_t gi = (size_t)(btbase + t) * DI + d;
        float dv = delta[gi];
        float xv = x[gi];
        float dx = dv * xv;
        sd += dv;
        const float4* bp = (const float4*)&Bs[t][0];
        float4 b0 = bp[0], b1 = bp[1], b2 = bp[2], b3 = bp[3];
        float bv[16] = {b0.x, b0.y, b0.z, b0.w, b1.x, b1.y, b1.z, b1.w,
                        b2.x, b2.y, b2.z, b2.w, b3.x, b3.y, b3.z, b3.w};
#pragma unroll
        for (int n = 0; n < 16; ++n) {
            float ab = exp2f(dv * a2[n]);
            h[n] = fmaf(ab, h[n], dx * bv[n]);
        }
    }
    size_t base = ((size_t)(b * NCH + c) * DS) * DI + d;
#pragma unroll
    for (int n = 0; n < 16; ++n) {
        hend[base + (size_t)n * DI] = h[n];
        cumA[base + (size_t)n * DI] = exp2f(a2[n] * sd);   // prod of exps = exp of sum
    }
}

// ---------------- K4: stitch chunk boundaries (in place: hend -> h_start) -
__global__ __launch_bounds__(256) void k_stitch(float* __restrict__ hend,
                                                const float* __restrict__ cumA) {
    int tid = blockIdx.x * 256 + threadIdx.x;   // 65536 threads
    int d = tid & (DI - 1);
    int n = (tid >> 11) & 15;
    int b = tid >> 15;
    float hs = 0.f;
    for (int c = 0; c < NCH; ++c) {
        size_t idx = ((size_t)((b * NCH + c) * DS + n)) * DI + d;
        float he = hend[idx];
        float ca = cumA[idx];
        hend[idx] = hs;           // overwrite with h_start of this chunk
        hs = ca * hs + he;
    }
}

// ---------------- K5: final scan with h_start, emit y (over delta buffer) -
__global__ __launch_bounds__(256) void k_scan2(float* __restrict__ delta_y,  // delta in, y out (same buffer)
                                               const float* __restrict__ x,
                                               const float* __restrict__ xz,
                                               const float* __restrict__ A_log,
                                               const float* __restrict__ hstart,
                                               const float* __restrict__ Dw) {
    __shared__ float Bs[CL][DS];
    __shared__ float Cs[CL][DS];
    const int tid = threadIdx.x;
    const int d = blockIdx.x * 256 + tid;
    const int c = blockIdx.y;
    const int b = blockIdx.z;
    const int btbase = b * SEQ + c * CL;

    for (int i = tid; i < CL * DS; i += 256) {
        int t = i >> 4;
        int n = i & 15;
        Bs[t][n] = xz[(size_t)(btbase + t) * P + DR + n];
        Cs[t][n] = xz[(size_t)(btbase + t) * P + DR + DS + n];
    }
    float a2[16];
#pragma unroll
    for (int n = 0; n < 16; ++n)
        a2[n] = -__expf(A_log[(size_t)d * DS + n]) * 1.4426950408889634f;

    size_t base = ((size_t)(b * NCH + c) * DS) * DI + d;
    float h[16];
#pragma unroll
    for (int n = 0; n < 16; ++n) h[n] = hstart[base + (size_t)n * DI];
    float Dv = Dw[d];
    __syncthreads();

    for (int t = 0; t < CL; ++t) {
        size_t gi = (size_t)(btbase + t) * DI + d;
        float dv = delta_y[gi];
        float xv = x[gi];
        float dx = dv * xv;
        const float4* bp = (const float4*)&Bs[t][0];
        float4 b0 = bp[0], b1 = bp[1], b2 = bp[2], b3 = bp[3];
        const float4* cp = (const float4*)&Cs[t][0];
        float4 c0 = cp[0], c1 = cp[1], c2 = cp[2], c3 = cp[3];
        float bv[16] = {b0.x, b0.y, b0.z, b0.w, b1.x, b1.y, b1.z, b1.w,
                        b2.x, b2.y, b2.z, b2.w, b3.x, b3.y, b3.z, b3.w};
        float cv[16] = {c0.x, c0.y, c0.z, c0.w, c1.x, c1.y, c1.z, c1.w,
                        c2.x, c2.y, c2.z, c2.w, c3.x, c3.y, c3.z, c3.w};
        float y = Dv * xv;
#pragma unroll
        for (int n = 0; n < 16; ++n) {
            float ab = exp2f(dv * a2[n]);
            h[n] = fmaf(ab, h[n], dx * bv[n]);
            y = fmaf(h[n], cv[n], y);
        }
        delta_y[gi] = y;   // safe: this thread already consumed delta[gi]
    }
}

extern "C" void kernel_launch(void* const* d_in, const int* in_sizes, int n_in,
                              void* d_out, int out_size, void* d_ws, size_t ws_size,
                              hipStream_t stream) {
    const float* x    = (const float*)d_in[0];   // (2,2048,2048)
    const float* xpw  = (const float*)d_in[1];   // (96,2048)
    const float* dtw  = (const float*)d_in[2];   // (2048,64)
    const float* dtb  = (const float*)d_in[3];   // (2048,)
    const float* Alog = (const float*)d_in[4];   // (2048,16)
    const float* Dw   = (const float*)d_in[5];   // (2048,)
    float* out = (float*)d_out;                  // (2,2048,2048) fp32 — holds delta, then y

    float* ws    = (float*)d_ws;
    float* xz    = ws + WS_XZ;
    float* parts = ws + WS_PARTS;
    float* dtwT  = ws + WS_DTWT;
    float* hend  = ws + WS_HEND;
    float* cumA  = ws + WS_CUMA;

    k_transpose<<<dim3(131072 / 256), 256, 0, stream>>>(dtw, dtwT);
    k_proj1<<<dim3(BT_ROWS / 64, KS), 256, 0, stream>>>(x, xpw, parts);
    k_reduce<<<dim3(BT_ROWS * P / 256), 256, 0, stream>>>(parts, xz);
    k_proj2<<<dim3(BT_ROWS / 16, DI / 256), 256, 0, stream>>>(xz, dtwT, dtb, out);
    k_scan1<<<dim3(DI / 256, NCH, BATCH), 256, 0, stream>>>(out, x, xz, Alog, hend, cumA);
    k_stitch<<<dim3(BATCH * DS * DI / 256), 256, 0, stream>>>(hend, cumA);
    k_scan2<<<dim3(DI / 256, NCH, BATCH), 256, 0, stream>>>(out, x, xz, Alog, hend, Dw);
}